// Round 7
// baseline (624.396 us; speedup 1.0000x reference)
//
#include <hip/hip_runtime.h>
#include <hip/hip_fp16.h>
#include <math.h>

#define CH    64
#define KT    343
#define HIDD  256

typedef __attribute__((ext_vector_type(8))) _Float16 half8;
typedef __attribute__((ext_vector_type(4))) _Float16 half4;
typedef __attribute__((ext_vector_type(4))) float f32x4;
struct H24 { __half2 x, y, z, w; };

// ---------------- Kernel P1: weight casts/transposes (f16) ----------------
__global__ __launch_bounds__(256) void prep_w_kernel(
    const float* __restrict__ W1, const float* __restrict__ W2,
    const float* __restrict__ W3, _Float16* __restrict__ W1h,
    _Float16* __restrict__ W2Th, _Float16* __restrict__ W3Th) {
  const int t = blockIdx.x * 256 + threadIdx.x;
  const int step = gridDim.x * 256;
  for (int e = t; e < KT * CH; e += step) W1h[e] = (_Float16)W1[e];
  for (int e = t; e < CH * HIDD; e += step) {       // W2 [64,256] -> W2T [256,64]
    int k = e >> 8, n = e & 255;
    W2Th[n * CH + k] = (_Float16)W2[e];
  }
  for (int e = t; e < HIDD * CH; e += step) {       // W3 [256,64] -> W3T [64,256]
    int k = e >> 6, n = e & 63;
    W3Th[n * HIDD + k] = (_Float16)W3[e];
  }
}

// ---------------- Kernel P2: x -> f16, plus one zero row at index N --------
__global__ __launch_bounds__(256) void xcast_kernel(
    const float* __restrict__ x, _Float16* __restrict__ xh, int nelem) {
  const int tot4 = nelem / 4 + 16;     // includes the 64-elem zero pad row
  for (int q = blockIdx.x * 256 + threadIdx.x; q < tot4; q += gridDim.x * 256) {
    const int eb = q * 4;
    float4 v = (eb < nelem) ? *(const float4*)(x + eb) : make_float4(0.f, 0.f, 0.f, 0.f);
    half4 o;
    o[0] = (_Float16)v.x; o[1] = (_Float16)v.y;
    o[2] = (_Float16)v.z; o[3] = (_Float16)v.w;
    *(half4*)(xh + eb) = o;
  }
}

// ---------------- Fused: depthwise conv + GN + MFMA MLP + residual ---------
// 256 threads = 4 waves; wave handles 8 voxels in conv (8 lanes/voxel,
// 8 f16 ch/lane). Conv inner loop is a depth-2 software pipeline: gathers
// for chunk ck+1 are in flight while chunk ck is consumed; neighbor-index
// words are prefetched 2 chunks ahead. launch_bounds(256,2) lifts the VGPR
// cap so the gather buffers stay in registers (round-6 failure: VGPR=36
// forced per-tap serialization).
#define ISSUE(buf, vi)                                                    \
  _Pragma("unroll")                                                       \
  for (int j = 0; j < 8; ++j) {                                           \
    const int idx_ = __builtin_amdgcn_ds_bpermute(pb + 4 * j, (vi));      \
    buf[j] = *(const uint4*)(xb + (((unsigned)idx_ << 7) + (unsigned)e16)); \
  }

#define CONSUME(buf, ck)                                                  \
  {                                                                       \
    const char* wp_ = wb + (ck) * 1024;                                   \
    _Pragma("unroll")                                                     \
    for (int j = 0; j < 8; ++j) {                                         \
      const uint4 wv4_ = *(const uint4*)(wp_ + j * 128 + e16);            \
      const H24 gh_ = __builtin_bit_cast(H24, buf[j]);                    \
      const H24 wh_ = __builtin_bit_cast(H24, wv4_);                      \
      acc0 = __hfma2(gh_.x, wh_.x, acc0);                                 \
      acc1 = __hfma2(gh_.y, wh_.y, acc1);                                 \
      acc2 = __hfma2(gh_.z, wh_.z, acc2);                                 \
      acc3 = __hfma2(gh_.w, wh_.w, acc3);                                 \
    }                                                                     \
  }

__global__ __launch_bounds__(256, 2) void fused_kernel(
    const _Float16* __restrict__ xh, const float* __restrict__ x,
    const int* __restrict__ nbr, const _Float16* __restrict__ W1h,
    const float* __restrict__ b1, const float* __restrict__ gamma,
    const float* __restrict__ beta, const _Float16* __restrict__ W2Th,
    const float* __restrict__ b2, const _Float16* __restrict__ W3Th,
    const float* __restrict__ b3, float* __restrict__ out, int N) {
  __shared__ __align__(16) _Float16 hs[32][CH + 8];     // 4.6 KB
  __shared__ __align__(16) _Float16 gs[32][HIDD + 8];   // 16.9 KB

  const int t = threadIdx.x;
  const int wv = t >> 6;
  const int lane = t & 63;
  const int g = lane >> 3;           // voxel within wave's group of 8
  const int e = lane & 7;            // channel oct: channels e*8 .. e*8+7
  const int e16 = e << 4;            // byte offset within a 128B f16 row
  const int pb = (lane & 56) << 2;   // ds_bpermute base: lane-group start *4
  const int vbase = blockIdx.x * 32;
  const int vb = __builtin_amdgcn_readfirstlane(vbase + wv * 8);

  // ---- phase 1: depthwise gather conv, depth-2 pipelined ----
  const int* nbw = nbr + (size_t)vb * KT;
  const int nbo = g * KT + e;        // this lane streams taps e, e+8, ...
  const char* xb = (const char*)xh;
  const char* wb = (const char*)W1h;

  __half2 acc0 = __float2half2_rn(0.f), acc1 = acc0, acc2 = acc0, acc3 = acc0;

  uint4 ga[8], gb[8];
  int viA = nbw[nbo];                // chunk 0 indices
  int viB = nbw[nbo + 8];            // chunk 1 indices
  ISSUE(ga, viA);

  for (int ck = 0; ck < 42; ck += 2) {
    const int offn = (ck < 40) ? (ck + 2) * 8 : 335;   // last prefetch = tail
    const int viC = nbw[nbo + offn];
    ISSUE(gb, viB);
    CONSUME(ga, ck);
    const int offm = (ck < 40) ? (ck + 3) * 8 : 335;
    const int viD = nbw[nbo + offm];
    if (ck < 40) ISSUE(ga, viC);
    CONSUME(gb, ck + 1);
    viA = viC; viB = viD;
  }

  {  // tail: taps 336..342 (viA holds taps 335..342; skip j=0)
    const char* wp = wb + 335 * 128;
#pragma unroll
    for (int j = 1; j < 8; ++j) {
      const int idx = __builtin_amdgcn_ds_bpermute(pb + 4 * j, viA);
      const uint4 gv = *(const uint4*)(xb + (((unsigned)idx << 7) + (unsigned)e16));
      const uint4 wv4 = *(const uint4*)(wp + j * 128 + e16);
      const H24 gh = __builtin_bit_cast(H24, gv);
      const H24 wh = __builtin_bit_cast(H24, wv4);
      acc0 = __hfma2(gh.x, wh.x, acc0);
      acc1 = __hfma2(gh.y, wh.y, acc1);
      acc2 = __hfma2(gh.z, wh.z, acc2);
      acc3 = __hfma2(gh.w, wh.w, acc3);
    }
  }

  // ---- phase 2: bias + GroupNorm over the 8-lane voxel group ----
  float fa[8];
  fa[0] = __low2float(acc0); fa[1] = __high2float(acc0);
  fa[2] = __low2float(acc1); fa[3] = __high2float(acc1);
  fa[4] = __low2float(acc2); fa[5] = __high2float(acc2);
  fa[6] = __low2float(acc3); fa[7] = __high2float(acc3);
  {
    float4 blo = *(const float4*)(b1 + e * 8);
    float4 bhi = *(const float4*)(b1 + e * 8 + 4);
    fa[0] += blo.x; fa[1] += blo.y; fa[2] += blo.z; fa[3] += blo.w;
    fa[4] += bhi.x; fa[5] += bhi.y; fa[6] += bhi.z; fa[7] += bhi.w;
  }
  float s = 0.f, ss = 0.f;
#pragma unroll
  for (int d = 0; d < 8; ++d) { s += fa[d]; ss += fa[d] * fa[d]; }
  s += __shfl_xor(s, 1); ss += __shfl_xor(ss, 1);
  s += __shfl_xor(s, 2); ss += __shfl_xor(ss, 2);
  s += __shfl_xor(s, 4); ss += __shfl_xor(ss, 4);
  const float mu = s * (1.0f / 64.0f);
  const float var = ss * (1.0f / 64.0f) - mu * mu;
  const float inv = rsqrtf(var + 1e-5f);
  {
    float4 glo = *(const float4*)(gamma + e * 8);
    float4 ghi = *(const float4*)(gamma + e * 8 + 4);
    float4 tlo = *(const float4*)(beta + e * 8);
    float4 thi = *(const float4*)(beta + e * 8 + 4);
    const float gm[8] = {glo.x, glo.y, glo.z, glo.w, ghi.x, ghi.y, ghi.z, ghi.w};
    const float bt[8] = {tlo.x, tlo.y, tlo.z, tlo.w, thi.x, thi.y, thi.z, thi.w};
    half8 hv;
#pragma unroll
    for (int d = 0; d < 8; ++d)
      hv[d] = (_Float16)((fa[d] - mu) * inv * gm[d] + bt[d]);
    *(half8*)&hs[wv * 8 + g][e * 8] = hv;
  }
  __syncthreads();

  // ---- phase 3: GEMM1 [32,64]x[64,256] + GELU -> gs ----
  const int row16 = lane & 15, quad = lane >> 4;
  half8 afr[2][2];
#pragma unroll
  for (int rt = 0; rt < 2; ++rt)
#pragma unroll
    for (int ks = 0; ks < 2; ++ks)
      afr[rt][ks] = *(const half8*)&hs[rt * 16 + row16][ks * 32 + quad * 8];

#pragma unroll
  for (int cl = 0; cl < 4; ++cl) {
    const int n = wv * 64 + cl * 16 + row16;
    f32x4 a0 = {0.f, 0.f, 0.f, 0.f}, a1 = {0.f, 0.f, 0.f, 0.f};
#pragma unroll
    for (int ks = 0; ks < 2; ++ks) {
      half8 bfr = *(const half8*)(W2Th + (size_t)n * CH + ks * 32 + quad * 8);
      a0 = __builtin_amdgcn_mfma_f32_16x16x32_f16(afr[0][ks], bfr, a0, 0, 0, 0);
      a1 = __builtin_amdgcn_mfma_f32_16x16x32_f16(afr[1][ks], bfr, a1, 0, 0, 0);
    }
    const float bias = b2[n];
#pragma unroll
    for (int r = 0; r < 4; ++r) {
      float z0 = a0[r] + bias;
      float z1 = a1[r] + bias;
      gs[quad * 4 + r][n]      = (_Float16)(0.5f * z0 * (1.0f + erff(z0 * 0.70710678118654752f)));
      gs[16 + quad * 4 + r][n] = (_Float16)(0.5f * z1 * (1.0f + erff(z1 * 0.70710678118654752f)));
    }
  }
  __syncthreads();

  // ---- phase 4: GEMM2 [32,256]x[256,64] + bias + residual ----
  f32x4 o0 = {0.f, 0.f, 0.f, 0.f}, o1 = {0.f, 0.f, 0.f, 0.f};
  const int oc = wv * 16 + row16;
#pragma unroll
  for (int ks = 0; ks < 8; ++ks) {
    half8 bfr = *(const half8*)(W3Th + (size_t)oc * HIDD + ks * 32 + quad * 8);
    half8 a20 = *(const half8*)&gs[row16][ks * 32 + quad * 8];
    half8 a21 = *(const half8*)&gs[16 + row16][ks * 32 + quad * 8];
    o0 = __builtin_amdgcn_mfma_f32_16x16x32_f16(a20, bfr, o0, 0, 0, 0);
    o1 = __builtin_amdgcn_mfma_f32_16x16x32_f16(a21, bfr, o1, 0, 0, 0);
  }
  const float bias3 = b3[oc];
#pragma unroll
  for (int r = 0; r < 4; ++r) {
    size_t v0 = (size_t)vbase + quad * 4 + r;
    size_t v1 = (size_t)vbase + 16 + quad * 4 + r;
    out[v0 * CH + oc] = o0[r] + bias3 + x[v0 * CH + oc];
    out[v1 * CH + oc] = o1[r] + bias3 + x[v1 * CH + oc];
  }
}

extern "C" void kernel_launch(void* const* d_in, const int* in_sizes, int n_in,
                              void* d_out, int out_size, void* d_ws, size_t ws_size,
                              hipStream_t stream) {
  const float* x_feat = (const float*)d_in[0];
  const int*   nbr    = (const int*)d_in[1];
  const float* W1     = (const float*)d_in[2];
  const float* b1     = (const float*)d_in[3];
  const float* gamma  = (const float*)d_in[4];
  const float* beta   = (const float*)d_in[5];
  const float* W2     = (const float*)d_in[6];
  const float* b2     = (const float*)d_in[7];
  const float* W3     = (const float*)d_in[8];
  const float* b3     = (const float*)d_in[9];
  float* out = (float*)d_out;

  const int N = in_sizes[0] / CH;      // 100000 (divisible by 32)

  char* ws = (char*)d_ws;
  size_t off = 0;
  _Float16* xh = (_Float16*)(ws + off);
  off += (((size_t)(N + 1) * CH * 2) + 255) & ~(size_t)255;   // x f16 + zero row
  _Float16* W1h = (_Float16*)(ws + off);
  off += ((size_t)KT * CH * 2 + 255) & ~(size_t)255;
  _Float16* W2Th = (_Float16*)(ws + off);
  off += ((size_t)HIDD * CH * 2 + 255) & ~(size_t)255;
  _Float16* W3Th = (_Float16*)(ws + off);

  hipLaunchKernelGGL(prep_w_kernel, dim3(32), dim3(256), 0, stream,
                     W1, W2, W3, W1h, W2Th, W3Th);
  hipLaunchKernelGGL(xcast_kernel, dim3(1024), dim3(256), 0, stream,
                     x_feat, xh, N * CH);
  hipLaunchKernelGGL(fused_kernel, dim3(N / 32), dim3(256), 0, stream,
                     xh, x_feat, nbr, W1h, b1, gamma, beta,
                     W2Th, b2, W3Th, b3, out, N);
}

// Round 8
// 440.733 us; speedup vs baseline: 1.4167x; 1.4167x over previous
//
#include <hip/hip_runtime.h>
#include <hip/hip_fp16.h>
#include <math.h>

#define CH    64
#define KT    343
#define HIDD  256

typedef __attribute__((ext_vector_type(8))) _Float16 half8;
typedef __attribute__((ext_vector_type(4))) _Float16 half4;
typedef __attribute__((ext_vector_type(4))) float f32x4;
struct H24 { __half2 x, y, z, w; };

#define MEMBAR() asm volatile("" ::: "memory")

// ---------------- Kernel P1: weight casts/transposes (f16) ----------------
__global__ __launch_bounds__(256) void prep_w_kernel(
    const float* __restrict__ W1, const float* __restrict__ W2,
    const float* __restrict__ W3, _Float16* __restrict__ W1h,
    _Float16* __restrict__ W2Th, _Float16* __restrict__ W3Th) {
  const int t = blockIdx.x * 256 + threadIdx.x;
  const int step = gridDim.x * 256;
  for (int e = t; e < KT * CH; e += step) W1h[e] = (_Float16)W1[e];
  for (int e = t; e < CH * HIDD; e += step) {       // W2 [64,256] -> W2T [256,64]
    int k = e >> 8, n = e & 255;
    W2Th[n * CH + k] = (_Float16)W2[e];
  }
  for (int e = t; e < HIDD * CH; e += step) {       // W3 [256,64] -> W3T [64,256]
    int k = e >> 6, n = e & 63;
    W3Th[n * HIDD + k] = (_Float16)W3[e];
  }
}

// ---------------- Kernel P2: x -> f16, plus one zero row at index N --------
__global__ __launch_bounds__(256) void xcast_kernel(
    const float* __restrict__ x, _Float16* __restrict__ xh, int nelem) {
  const int tot4 = nelem / 4 + 16;     // includes the 64-elem zero pad row
  for (int q = blockIdx.x * 256 + threadIdx.x; q < tot4; q += gridDim.x * 256) {
    const int eb = q * 4;
    float4 v = (eb < nelem) ? *(const float4*)(x + eb) : make_float4(0.f, 0.f, 0.f, 0.f);
    half4 o;
    o[0] = (_Float16)v.x; o[1] = (_Float16)v.y;
    o[2] = (_Float16)v.z; o[3] = (_Float16)v.w;
    *(half4*)(xh + eb) = o;
  }
}

// ---------------- Fused: depthwise conv + GN + MFMA MLP + residual ---------
// 4 waves x 8 voxels. Gather batches of 8 uint4 are pinned in VGPRs by
// asm memory barriers (round 6/7 failure: scheduler sank the loads and
// re-serialized). W1 lives in LDS (broadcast ds_read), so consume has no
// VMEM latency. gs aliases the W1 LDS region after conv completes.
#define ISSUE8(buf, vi)                                                     \
  { _Pragma("unroll") for (int p = 0; p < 8; ++p) {                         \
      const int idx_ = __builtin_amdgcn_ds_bpermute(pb + 4 * p, (vi));      \
      buf[p] = *(const uint4*)(xb + (((unsigned)idx_ << 7) + (unsigned)e16)); } }

#define CONSUME8(buf, tapbase)                                              \
  { _Pragma("unroll") for (int p = 0; p < 8; ++p) {                         \
      const uint4 wq_ = *(const uint4*)&W1s[(((tapbase) + p) << 7) + e16];  \
      const H24 gh_ = __builtin_bit_cast(H24, buf[p]);                      \
      const H24 wh_ = __builtin_bit_cast(H24, wq_);                         \
      acc0 = __hfma2(gh_.x, wh_.x, acc0);                                   \
      acc1 = __hfma2(gh_.y, wh_.y, acc1);                                   \
      acc2 = __hfma2(gh_.z, wh_.z, acc2);                                   \
      acc3 = __hfma2(gh_.w, wh_.w, acc3); } }

__global__ __launch_bounds__(256, 3) void fused_kernel(
    const _Float16* __restrict__ xh, const float* __restrict__ x,
    const int* __restrict__ nbr, const _Float16* __restrict__ W1h,
    const float* __restrict__ b1, const float* __restrict__ gamma,
    const float* __restrict__ beta, const _Float16* __restrict__ W2Th,
    const float* __restrict__ b2, const _Float16* __restrict__ W3Th,
    const float* __restrict__ b3, float* __restrict__ out, int N) {
  __shared__ __align__(16) char W1s[43904];            // 343 taps x 128B; gs aliases later
  __shared__ __align__(16) _Float16 hs[32][CH + 8];    // 4.6 KB (not aliased)
  _Float16 (*gs)[HIDD + 8] = (_Float16 (*)[HIDD + 8])W1s;  // 16.9 KB, used post-conv

  const int t = threadIdx.x;
  const int wvid = t >> 6;
  const int lane = t & 63;
  const int g = lane >> 3;           // voxel within wave's group of 8
  const int e = lane & 7;            // channel oct
  const int e16 = e << 4;
  const int pb = (lane & 56) << 2;   // bpermute group base *4
  const int vbase = blockIdx.x * 32;
  const int vb = __builtin_amdgcn_readfirstlane(vbase + wvid * 8);

  // stage W1 into LDS (2744 uint4)
  {
    const uint4* src = (const uint4*)W1h;
    uint4* dst = (uint4*)W1s;
    for (int q = t; q < 2744; q += 256) dst[q] = src[q];
  }

  const int* nbw = nbr + (size_t)vb * KT;
  const int nbo = g * KT + e;
  const char* xb = (const char*)xh;

  __half2 acc0 = __float2half2_rn(0.f), acc1 = acc0, acc2 = acc0, acc3 = acc0;

  uint4 ga[8], gb[8];
  int viA = nbw[nbo];                // chunk 0
  int viB = nbw[nbo + 8];            // chunk 1
  ISSUE8(ga, viA);                   // overlaps W1 staging
  __syncthreads();                   // W1s ready

  for (int ck = 0; ck < 42; ck += 2) {
    const int viC = nbw[nbo + ((ck + 2 < 42) ? (ck + 2) * 8 : 335)];
    MEMBAR();
    ISSUE8(gb, viB);
    MEMBAR();
    CONSUME8(ga, ck * 8);
    const int viD = nbw[nbo + ((ck + 3 < 42) ? (ck + 3) * 8 : 335)];
    MEMBAR();
    if (ck + 2 < 42) ISSUE8(ga, viC);
    MEMBAR();
    CONSUME8(gb, ck * 8 + 8);
    viB = viD;
  }

  {  // tail: taps 336..342 (viB holds taps 335..342; use j=1..7)
    uint4 gt[7];
#pragma unroll
    for (int p = 0; p < 7; ++p) {
      const int idx = __builtin_amdgcn_ds_bpermute(pb + 4 * (p + 1), viB);
      gt[p] = *(const uint4*)(xb + (((unsigned)idx << 7) + (unsigned)e16));
    }
    MEMBAR();
#pragma unroll
    for (int p = 0; p < 7; ++p) {
      const uint4 wq = *(const uint4*)&W1s[((336 + p) << 7) + e16];
      const H24 gh = __builtin_bit_cast(H24, gt[p]);
      const H24 wh = __builtin_bit_cast(H24, wq);
      acc0 = __hfma2(gh.x, wh.x, acc0);
      acc1 = __hfma2(gh.y, wh.y, acc1);
      acc2 = __hfma2(gh.z, wh.z, acc2);
      acc3 = __hfma2(gh.w, wh.w, acc3);
    }
  }

  // ---- bias + GroupNorm over the 8-lane voxel group ----
  float fa[8];
  fa[0] = __low2float(acc0); fa[1] = __high2float(acc0);
  fa[2] = __low2float(acc1); fa[3] = __high2float(acc1);
  fa[4] = __low2float(acc2); fa[5] = __high2float(acc2);
  fa[6] = __low2float(acc3); fa[7] = __high2float(acc3);
  {
    float4 blo = *(const float4*)(b1 + e * 8);
    float4 bhi = *(const float4*)(b1 + e * 8 + 4);
    fa[0] += blo.x; fa[1] += blo.y; fa[2] += blo.z; fa[3] += blo.w;
    fa[4] += bhi.x; fa[5] += bhi.y; fa[6] += bhi.z; fa[7] += bhi.w;
  }
  float s = 0.f, ss = 0.f;
#pragma unroll
  for (int d = 0; d < 8; ++d) { s += fa[d]; ss += fa[d] * fa[d]; }
  s += __shfl_xor(s, 1); ss += __shfl_xor(ss, 1);
  s += __shfl_xor(s, 2); ss += __shfl_xor(ss, 2);
  s += __shfl_xor(s, 4); ss += __shfl_xor(ss, 4);
  const float mu = s * (1.0f / 64.0f);
  const float var = ss * (1.0f / 64.0f) - mu * mu;
  const float inv = rsqrtf(var + 1e-5f);
  {
    float4 glo = *(const float4*)(gamma + e * 8);
    float4 ghi = *(const float4*)(gamma + e * 8 + 4);
    float4 tlo = *(const float4*)(beta + e * 8);
    float4 thi = *(const float4*)(beta + e * 8 + 4);
    const float gm[8] = {glo.x, glo.y, glo.z, glo.w, ghi.x, ghi.y, ghi.z, ghi.w};
    const float bt[8] = {tlo.x, tlo.y, tlo.z, tlo.w, thi.x, thi.y, thi.z, thi.w};
    half8 hv;
#pragma unroll
    for (int d = 0; d < 8; ++d)
      hv[d] = (_Float16)((fa[d] - mu) * inv * gm[d] + bt[d]);
    *(half8*)&hs[wvid * 8 + g][e * 8] = hv;
  }
  __syncthreads();   // all conv W1s reads done; gs may now overwrite W1s

  // ---- GEMM1 [32,64]x[64,256] + GELU -> gs ----
  const int row16 = lane & 15, quad = lane >> 4;
  half8 afr[2][2];
#pragma unroll
  for (int rt = 0; rt < 2; ++rt)
#pragma unroll
    for (int ks = 0; ks < 2; ++ks)
      afr[rt][ks] = *(const half8*)&hs[rt * 16 + row16][ks * 32 + quad * 8];

#pragma unroll
  for (int cl = 0; cl < 4; ++cl) {
    const int n = wvid * 64 + cl * 16 + row16;
    f32x4 a0 = {0.f, 0.f, 0.f, 0.f}, a1 = {0.f, 0.f, 0.f, 0.f};
#pragma unroll
    for (int ks = 0; ks < 2; ++ks) {
      half8 bfr = *(const half8*)(W2Th + (size_t)n * CH + ks * 32 + quad * 8);
      a0 = __builtin_amdgcn_mfma_f32_16x16x32_f16(afr[0][ks], bfr, a0, 0, 0, 0);
      a1 = __builtin_amdgcn_mfma_f32_16x16x32_f16(afr[1][ks], bfr, a1, 0, 0, 0);
    }
    const float bias = b2[n];
#pragma unroll
    for (int r = 0; r < 4; ++r) {
      float z0 = a0[r] + bias;
      float z1 = a1[r] + bias;
      gs[quad * 4 + r][n]      = (_Float16)(0.5f * z0 * (1.0f + erff(z0 * 0.70710678118654752f)));
      gs[16 + quad * 4 + r][n] = (_Float16)(0.5f * z1 * (1.0f + erff(z1 * 0.70710678118654752f)));
    }
  }
  __syncthreads();

  // ---- GEMM2 [32,256]x[256,64] + bias + residual ----
  f32x4 o0 = {0.f, 0.f, 0.f, 0.f}, o1 = {0.f, 0.f, 0.f, 0.f};
  const int oc = wvid * 16 + row16;
#pragma unroll
  for (int ks = 0; ks < 8; ++ks) {
    half8 bfr = *(const half8*)(W3Th + (size_t)oc * HIDD + ks * 32 + quad * 8);
    half8 a20 = *(const half8*)&gs[row16][ks * 32 + quad * 8];
    half8 a21 = *(const half8*)&gs[16 + row16][ks * 32 + quad * 8];
    o0 = __builtin_amdgcn_mfma_f32_16x16x32_f16(a20, bfr, o0, 0, 0, 0);
    o1 = __builtin_amdgcn_mfma_f32_16x16x32_f16(a21, bfr, o1, 0, 0, 0);
  }
  const float bias3 = b3[oc];
#pragma unroll
  for (int r = 0; r < 4; ++r) {
    size_t v0 = (size_t)vbase + quad * 4 + r;
    size_t v1 = (size_t)vbase + 16 + quad * 4 + r;
    out[v0 * CH + oc] = o0[r] + bias3 + x[v0 * CH + oc];
    out[v1 * CH + oc] = o1[r] + bias3 + x[v1 * CH + oc];
  }
}

extern "C" void kernel_launch(void* const* d_in, const int* in_sizes, int n_in,
                              void* d_out, int out_size, void* d_ws, size_t ws_size,
                              hipStream_t stream) {
  const float* x_feat = (const float*)d_in[0];
  const int*   nbr    = (const int*)d_in[1];
  const float* W1     = (const float*)d_in[2];
  const float* b1     = (const float*)d_in[3];
  const float* gamma  = (const float*)d_in[4];
  const float* beta   = (const float*)d_in[5];
  const float* W2     = (const float*)d_in[6];
  const float* b2     = (const float*)d_in[7];
  const float* W3     = (const float*)d_in[8];
  const float* b3     = (const float*)d_in[9];
  float* out = (float*)d_out;

  const int N = in_sizes[0] / CH;      // 100000 (divisible by 32)

  char* ws = (char*)d_ws;
  size_t off = 0;
  _Float16* xh = (_Float16*)(ws + off);
  off += (((size_t)(N + 1) * CH * 2) + 255) & ~(size_t)255;   // x f16 + zero row
  _Float16* W1h = (_Float16*)(ws + off);
  off += ((size_t)KT * CH * 2 + 255) & ~(size_t)255;
  _Float16* W2Th = (_Float16*)(ws + off);
  off += ((size_t)HIDD * CH * 2 + 255) & ~(size_t)255;
  _Float16* W3Th = (_Float16*)(ws + off);

  hipLaunchKernelGGL(prep_w_kernel, dim3(32), dim3(256), 0, stream,
                     W1, W2, W3, W1h, W2Th, W3Th);
  hipLaunchKernelGGL(xcast_kernel, dim3(1024), dim3(256), 0, stream,
                     x_feat, xh, N * CH);
  hipLaunchKernelGGL(fused_kernel, dim3(N / 32), dim3(256), 0, stream,
                     xh, x_feat, nbr, W1h, b1, gamma, beta,
                     W2Th, b2, W3Th, b3, out, N);
}